// Round 2
// baseline (5168.819 us; speedup 1.0000x reference)
//
#include <hip/hip_runtime.h>
#include <hip/hip_fp16.h>
#include <stdint.h>

typedef _Float16 f16;
typedef _Float16 f16x8 __attribute__((ext_vector_type(8)));
typedef _Float16 f16x4 __attribute__((ext_vector_type(4)));
typedef float f32x4 __attribute__((ext_vector_type(4)));

#define DEV __device__ __forceinline__

DEV void gload_lds16(const void* g, void* l) {
    __builtin_amdgcn_global_load_lds(
        (const __attribute__((address_space(1))) void*)g,
        (__attribute__((address_space(3))) void*)l, 16, 0, 0);
}

// ---------------------------------------------------------------------------
// Split-fp16 GEMM: C = (Ahi+Alo) @ (Bhi+Blo)^T   (drops lo*lo term, ~2^-22)
// A: [M,K] rows m0.., B: [N,K] rows n0.., lda=ldb=K. 128x128 tile, BK=32.
// EPI==0: write f32 C (ldc).  EPI==1: write (hi,lo) fp16 pair of (C + bias).
// ---------------------------------------------------------------------------
template <int EPI>
__global__ __launch_bounds__(256, 2) void gemm_split3(
    const f16* __restrict__ Ahi, const f16* __restrict__ Alo,
    const f16* __restrict__ Bhi, const f16* __restrict__ Blo,
    int K, int ldc,
    float* __restrict__ Cf, f16* __restrict__ Chi, f16* __restrict__ Clo,
    const float* __restrict__ bias)
{
    __shared__ alignas(16) f16 As_hi[128 * 32];
    __shared__ alignas(16) f16 As_lo[128 * 32];
    __shared__ alignas(16) f16 Bs_hi[128 * 32];
    __shared__ alignas(16) f16 Bs_lo[128 * 32];
    const int t = threadIdx.x;
    const int lane = t & 63;
    const int w = t >> 6;
    const size_t m0 = (size_t)blockIdx.y * 128;
    const size_t n0 = (size_t)blockIdx.x * 128;
    const int wrow = (w >> 1) * 64;
    const int wcol = (w & 1) * 64;

    f32x4 acc[4][4] = {};

    for (int k0 = 0; k0 < K; k0 += 32) {
        __syncthreads();
#pragma unroll
        for (int i = 0; i < 2; ++i) {
            const int c = i * 256 + t;
            const int row = c >> 2;
            const int col = (c & 3) << 3;
            const int loff = (i * 256 + w * 64) * 8;  // f16 elements
            const size_t ga = (m0 + row) * (size_t)K + k0 + col;
            const size_t gb = (n0 + row) * (size_t)K + k0 + col;
            gload_lds16(Ahi + ga, &As_hi[loff]);
            gload_lds16(Alo + ga, &As_lo[loff]);
            gload_lds16(Bhi + gb, &Bs_hi[loff]);
            gload_lds16(Blo + gb, &Bs_lo[loff]);
        }
        __syncthreads();
        const int fr = lane & 15;
        const int fk = (lane >> 4) << 3;
        f16x8 ah[4], al[4], bh[4], bl[4];
#pragma unroll
        for (int x = 0; x < 4; ++x) {
            ah[x] = *(const f16x8*)&As_hi[(wrow + x * 16 + fr) * 32 + fk];
            al[x] = *(const f16x8*)&As_lo[(wrow + x * 16 + fr) * 32 + fk];
            bh[x] = *(const f16x8*)&Bs_hi[(wcol + x * 16 + fr) * 32 + fk];
            bl[x] = *(const f16x8*)&Bs_lo[(wcol + x * 16 + fr) * 32 + fk];
        }
#pragma unroll
        for (int mi = 0; mi < 4; ++mi)
#pragma unroll
            for (int ni = 0; ni < 4; ++ni) {
                acc[mi][ni] = __builtin_amdgcn_mfma_f32_16x16x32_f16(ah[mi], bh[ni], acc[mi][ni], 0, 0, 0);
                acc[mi][ni] = __builtin_amdgcn_mfma_f32_16x16x32_f16(ah[mi], bl[ni], acc[mi][ni], 0, 0, 0);
                acc[mi][ni] = __builtin_amdgcn_mfma_f32_16x16x32_f16(al[mi], bh[ni], acc[mi][ni], 0, 0, 0);
            }
    }

    const int fr = lane & 15;
    const int fq = lane >> 4;
#pragma unroll
    for (int mi = 0; mi < 4; ++mi)
#pragma unroll
        for (int ni = 0; ni < 4; ++ni)
#pragma unroll
            for (int r = 0; r < 4; ++r) {
                const size_t row = m0 + wrow + mi * 16 + fq * 4 + r;
                const size_t col = n0 + wcol + ni * 16 + fr;
                float v = acc[mi][ni][r];
                if constexpr (EPI == 0) {
                    Cf[row * (size_t)ldc + col] = v;
                } else {
                    v += bias[col];
                    const f16 h = (f16)v;
                    Chi[row * (size_t)ldc + col] = h;
                    Clo[row * (size_t)ldc + col] = (f16)(v - (float)h);
                }
            }
}

// ---------------------------------------------------------------------------
// Single fp16 GEMM: C(fp16) = A @ B^T. A:[M,K] B:[N,K], lda=ldb=K.
// ---------------------------------------------------------------------------
__global__ __launch_bounds__(256, 4) void gemm_f16(
    const f16* __restrict__ A, const f16* __restrict__ B,
    int K, int ldc, f16* __restrict__ C)
{
    __shared__ alignas(16) f16 As[128 * 32];
    __shared__ alignas(16) f16 Bs[128 * 32];
    const int t = threadIdx.x;
    const int lane = t & 63;
    const int w = t >> 6;
    const size_t m0 = (size_t)blockIdx.y * 128;
    const size_t n0 = (size_t)blockIdx.x * 128;
    const int wrow = (w >> 1) * 64;
    const int wcol = (w & 1) * 64;

    f32x4 acc[4][4] = {};

    for (int k0 = 0; k0 < K; k0 += 32) {
        __syncthreads();
#pragma unroll
        for (int i = 0; i < 2; ++i) {
            const int c = i * 256 + t;
            const int row = c >> 2;
            const int col = (c & 3) << 3;
            const int loff = (i * 256 + w * 64) * 8;
            gload_lds16(A + (m0 + row) * (size_t)K + k0 + col, &As[loff]);
            gload_lds16(B + (n0 + row) * (size_t)K + k0 + col, &Bs[loff]);
        }
        __syncthreads();
        const int fr = lane & 15;
        const int fk = (lane >> 4) << 3;
        f16x8 a[4], b[4];
#pragma unroll
        for (int x = 0; x < 4; ++x) {
            a[x] = *(const f16x8*)&As[(wrow + x * 16 + fr) * 32 + fk];
            b[x] = *(const f16x8*)&Bs[(wcol + x * 16 + fr) * 32 + fk];
        }
#pragma unroll
        for (int mi = 0; mi < 4; ++mi)
#pragma unroll
            for (int ni = 0; ni < 4; ++ni)
                acc[mi][ni] = __builtin_amdgcn_mfma_f32_16x16x32_f16(a[mi], b[ni], acc[mi][ni], 0, 0, 0);
    }

    const int fr = lane & 15;
    const int fq = lane >> 4;
#pragma unroll
    for (int mi = 0; mi < 4; ++mi)
#pragma unroll
        for (int ni = 0; ni < 4; ++ni)
#pragma unroll
            for (int r = 0; r < 4; ++r) {
                const size_t row = m0 + wrow + mi * 16 + fq * 4 + r;
                const size_t col = n0 + wcol + ni * 16 + fr;
                C[row * (size_t)ldc + col] = (f16)acc[mi][ni][r];
            }
}

// ---------------------------------------------------------------------------
// Final GEMM: Out = tanh(cat @ B^T + bias), cat from 3 segments of K=1024
// each (A0=att_hi, A1=ctx_ss, A2=ctx_es), B = Wlin fp16 [1024, 3072].
// ---------------------------------------------------------------------------
__global__ __launch_bounds__(256, 4) void gemm_final(
    const f16* __restrict__ A0, const f16* __restrict__ A1,
    const f16* __restrict__ A2, const f16* __restrict__ B,
    const float* __restrict__ bias, float* __restrict__ Out)
{
    __shared__ alignas(16) f16 As[128 * 32];
    __shared__ alignas(16) f16 Bs[128 * 32];
    const int t = threadIdx.x;
    const int lane = t & 63;
    const int w = t >> 6;
    const size_t m0 = (size_t)blockIdx.y * 128;
    const size_t n0 = (size_t)blockIdx.x * 128;
    const int wrow = (w >> 1) * 64;
    const int wcol = (w & 1) * 64;
    const int K = 3072;

    f32x4 acc[4][4] = {};

    for (int k0 = 0; k0 < K; k0 += 32) {
        const f16* Aseg = (k0 < 1024) ? A0 : (k0 < 2048) ? A1 : A2;
        const int kl = k0 & 1023;
        __syncthreads();
#pragma unroll
        for (int i = 0; i < 2; ++i) {
            const int c = i * 256 + t;
            const int row = c >> 2;
            const int col = (c & 3) << 3;
            const int loff = (i * 256 + w * 64) * 8;
            gload_lds16(Aseg + (m0 + row) * (size_t)1024 + kl + col, &As[loff]);
            gload_lds16(B + (n0 + row) * (size_t)K + k0 + col, &Bs[loff]);
        }
        __syncthreads();
        const int fr = lane & 15;
        const int fk = (lane >> 4) << 3;
        f16x8 a[4], b[4];
#pragma unroll
        for (int x = 0; x < 4; ++x) {
            a[x] = *(const f16x8*)&As[(wrow + x * 16 + fr) * 32 + fk];
            b[x] = *(const f16x8*)&Bs[(wcol + x * 16 + fr) * 32 + fk];
        }
#pragma unroll
        for (int mi = 0; mi < 4; ++mi)
#pragma unroll
            for (int ni = 0; ni < 4; ++ni)
                acc[mi][ni] = __builtin_amdgcn_mfma_f32_16x16x32_f16(a[mi], b[ni], acc[mi][ni], 0, 0, 0);
    }

    const int fr = lane & 15;
    const int fq = lane >> 4;
#pragma unroll
    for (int mi = 0; mi < 4; ++mi)
#pragma unroll
        for (int ni = 0; ni < 4; ++ni)
#pragma unroll
            for (int r = 0; r < 4; ++r) {
                const size_t row = m0 + wrow + mi * 16 + fq * 4 + r;
                const size_t col = n0 + wcol + ni * 16 + fr;
                Out[row * 1024 + col] = tanhf(acc[mi][ni][r] + bias[col]);
            }
}

// ---------------------------------------------------------------------------
// Row softmax: one block per row of length C*1024 f32, write fp16 weights
// to a separate output (possibly a row slice of a bigger matrix).
// ---------------------------------------------------------------------------
template <int C>
__global__ __launch_bounds__(256) void softmax_row(
    const float* __restrict__ S, f16* __restrict__ W)
{
    const float* s = S + (size_t)blockIdx.x * (C * 1024);
    f16* w = W + (size_t)blockIdx.x * (C * 1024);
    const int t = threadIdx.x;
    f32x4 v[C];
    float mx = -3.0e38f;
#pragma unroll
    for (int i = 0; i < C; ++i) {
        v[i] = *(const f32x4*)&s[(t + i * 256) * 4];
        mx = fmaxf(mx, fmaxf(fmaxf(v[i][0], v[i][1]), fmaxf(v[i][2], v[i][3])));
    }
#pragma unroll
    for (int off = 32; off; off >>= 1) mx = fmaxf(mx, __shfl_xor(mx, off));
    __shared__ float red[8];
    if ((t & 63) == 0) red[t >> 6] = mx;
    __syncthreads();
    mx = fmaxf(fmaxf(red[0], red[1]), fmaxf(red[2], red[3]));
    float sm = 0.f;
#pragma unroll
    for (int i = 0; i < C; ++i) {
        v[i][0] = __expf(v[i][0] - mx);
        v[i][1] = __expf(v[i][1] - mx);
        v[i][2] = __expf(v[i][2] - mx);
        v[i][3] = __expf(v[i][3] - mx);
        sm += (v[i][0] + v[i][1]) + (v[i][2] + v[i][3]);
    }
#pragma unroll
    for (int off = 32; off; off >>= 1) sm += __shfl_xor(sm, off);
    if ((t & 63) == 0) red[4 + (t >> 6)] = sm;
    __syncthreads();
    sm = (red[4] + red[5]) + (red[6] + red[7]);
    const float inv = 1.f / sm;
#pragma unroll
    for (int i = 0; i < C; ++i) {
        f16x4 o;
        o[0] = (f16)(v[i][0] * inv);
        o[1] = (f16)(v[i][1] * inv);
        o[2] = (f16)(v[i][2] * inv);
        o[3] = (f16)(v[i][3] * inv);
        *(f16x4*)&w[(t + i * 256) * 4] = o;
    }
}

// ---------------------------------------------------------------------------
// Transpose X[N,H] f32 -> Xt[H,N] fp16 (64x64 tiles via LDS)
// ---------------------------------------------------------------------------
__global__ __launch_bounds__(256) void transpose_f32_to_f16(
    const float* __restrict__ X, f16* __restrict__ Xt, int N, int H)
{
    __shared__ float tile[64][65];
    const int n0 = blockIdx.x * 64;
    const int h0 = blockIdx.y * 64;
    const int tx = threadIdx.x & 15;
    const int ty = threadIdx.x >> 4;
#pragma unroll
    for (int i = 0; i < 4; ++i) {
        const int r = ty + i * 16;
        const f32x4 vv = *(const f32x4*)&X[(size_t)(n0 + r) * H + h0 + tx * 4];
        tile[r][tx * 4 + 0] = vv[0];
        tile[r][tx * 4 + 1] = vv[1];
        tile[r][tx * 4 + 2] = vv[2];
        tile[r][tx * 4 + 3] = vv[3];
    }
    __syncthreads();
#pragma unroll
    for (int i = 0; i < 4; ++i) {
        const int hh = ty + i * 16;
        f16x4 o;
        o[0] = (f16)tile[tx * 4 + 0][hh];
        o[1] = (f16)tile[tx * 4 + 1][hh];
        o[2] = (f16)tile[tx * 4 + 2][hh];
        o[3] = (f16)tile[tx * 4 + 3][hh];
        *(f16x4*)&Xt[(size_t)(h0 + hh) * N + n0 + tx * 4] = o;
    }
}

// ---------------------------------------------------------------------------
// Elementwise converters
// ---------------------------------------------------------------------------
__global__ __launch_bounds__(256) void split_f32_f16(
    const float* __restrict__ X, f16* __restrict__ hi, f16* __restrict__ lo)
{
    const size_t i = ((size_t)blockIdx.x * 256 + threadIdx.x) * 4;
    const f32x4 v = *(const f32x4*)&X[i];
    f16x4 h, l;
#pragma unroll
    for (int j = 0; j < 4; ++j) {
        h[j] = (f16)v[j];
        l[j] = (f16)(v[j] - (float)h[j]);
    }
    *(f16x4*)&hi[i] = h;
    *(f16x4*)&lo[i] = l;
}

__global__ __launch_bounds__(256) void conv_f32_f16(
    const float* __restrict__ X, f16* __restrict__ Y)
{
    const size_t i = ((size_t)blockIdx.x * 256 + threadIdx.x) * 4;
    const f32x4 v = *(const f32x4*)&X[i];
    f16x4 h;
#pragma unroll
    for (int j = 0; j < 4; ++j) h[j] = (f16)v[j];
    *(f16x4*)&Y[i] = h;
}

// ---------------------------------------------------------------------------
extern "C" void kernel_launch(void* const* d_in, const int* in_sizes, int n_in,
                              void* d_out, int out_size, void* d_ws, size_t ws_size,
                              hipStream_t stream)
{
    (void)in_sizes; (void)n_in; (void)out_size;
    constexpr int Ns = 8192, Ne = 4096, M = 8192, H = 1024, K3 = 3072, AO = 1024;

    const float* Xss  = (const float*)d_in[0];
    const float* Xes  = (const float*)d_in[1];
    const float* Att  = (const float*)d_in[2];
    const float* Wss  = (const float*)d_in[3];
    const float* bss  = (const float*)d_in[4];
    const float* Wes  = (const float*)d_in[5];
    const float* bes  = (const float*)d_in[6];
    const float* Wlin = (const float*)d_in[7];
    const float* blin = (const float*)d_in[8];
    float* Out = (float*)d_out;

    // ---- workspace planning -------------------------------------------------
    char* base = (char*)d_ws;
    size_t off = 0;
    auto carve = [&](size_t bytes) {
        char* r = base + off;
        off = (off + bytes + 255) & ~(size_t)255;
        return r;
    };

    // Persistent region
    f16* Att_hi = (f16*)carve((size_t)M * H * 2);
    f16* Att_lo = (f16*)carve((size_t)M * H * 2);
    f16* Vtss   = (f16*)carve((size_t)H * Ns * 2);
    f16* Vtes   = (f16*)carve((size_t)H * Ne * 2);
    f16* Wl16   = (f16*)carve((size_t)AO * K3 * 2);
    char* Pbase = carve((size_t)(Ns + Ns + Ne + Ne) * H * 2);  // P hi/lo region
    f16* Pss_hi = (f16*)Pbase;
    f16* Pss_lo = Pss_hi + (size_t)Ns * H;
    f16* Pes_hi = Pss_lo + (size_t)Ns * H;
    f16* Pes_lo = Pes_hi + (size_t)Ne * H;

    const size_t persist_end = off;
    const size_t cap = (ws_size > persist_end) ? ws_size - persist_end : 0;
    char* R2 = base + persist_end;

    // Phase-A transient (X splits + W splits) lives at start of R2
    const size_t sizeA = (size_t)(2 * Ns + 2 * Ne) * H * 2 + (size_t)4 * H * H * 2;
    f16* Xss_hi = (f16*)R2;
    f16* Xss_lo = Xss_hi + (size_t)Ns * H;
    f16* Xes_hi = Xss_lo + (size_t)Ns * H;
    f16* Xes_lo = Xes_hi + (size_t)Ne * H;
    f16* Wss_hi = Xes_lo + (size_t)Ne * H;
    f16* Wss_lo = Wss_hi + (size_t)H * H;
    f16* Wes_hi = Wss_lo + (size_t)H * H;
    f16* Wes_lo = Wes_hi + (size_t)H * H;

    // Full path: overlay R2 (after stage 1) with full weight matrices + S chunk
    const size_t wtBytes = ((size_t)M * Ns + (size_t)M * Ne) * 2;  // 201.3 MB
    const size_t perRowS = (size_t)(Ns + Ne) * 4;
    int McF = 0;
    for (int mc = 4096; mc >= 128; mc >>= 1) {
        if (wtBytes + (size_t)mc * perRowS <= cap && sizeA <= cap) { McF = mc; break; }
    }

    if (McF > 0) {
        // ---------------- full-weight path ----------------
        f16* Wtss = (f16*)R2;                                  // [M, Ns]
        f16* Wtes = Wtss + (size_t)M * Ns;                     // [M, Ne]
        float* Sss = (float*)(Wtes + (size_t)M * Ne);          // [McF, Ns]
        float* Ses = Sss + (size_t)McF * Ns;                   // [McF, Ne]
        // Ctx aliased over dead P region (P dead after score GEMMs)
        f16* Ctxss = (f16*)Pbase;
        f16* Ctxes = Ctxss + (size_t)M * H;

        // stage 0
        split_f32_f16<<<(M * H) / 1024, 256, 0, stream>>>(Att, Att_hi, Att_lo);
        split_f32_f16<<<(Ns * H) / 1024, 256, 0, stream>>>(Xss, Xss_hi, Xss_lo);
        split_f32_f16<<<(Ne * H) / 1024, 256, 0, stream>>>(Xes, Xes_hi, Xes_lo);
        split_f32_f16<<<(H * H) / 1024, 256, 0, stream>>>(Wss, Wss_hi, Wss_lo);
        split_f32_f16<<<(H * H) / 1024, 256, 0, stream>>>(Wes, Wes_hi, Wes_lo);
        conv_f32_f16<<<(AO * K3) / 1024, 256, 0, stream>>>(Wlin, Wl16);
        transpose_f32_to_f16<<<dim3(Ns / 64, H / 64), 256, 0, stream>>>(Xss, Vtss, Ns, H);
        transpose_f32_to_f16<<<dim3(Ne / 64, H / 64), 256, 0, stream>>>(Xes, Vtes, Ne, H);

        // stage 1: projections (outputs in persistent P region)
        gemm_split3<1><<<dim3(H / 128, Ns / 128), 256, 0, stream>>>(
            Xss_hi, Xss_lo, Wss_hi, Wss_lo, H, H, nullptr, Pss_hi, Pss_lo, bss);
        gemm_split3<1><<<dim3(H / 128, Ne / 128), 256, 0, stream>>>(
            Xes_hi, Xes_lo, Wes_hi, Wes_lo, H, H, nullptr, Pes_hi, Pes_lo, bes);
        // (X/W transient region is dead from here; R2 overlay takes over)

        // stage 2a: scores + softmax -> full weight matrices
        for (int m0 = 0; m0 < M; m0 += McF) {
            gemm_split3<0><<<dim3(Ns / 128, McF / 128), 256, 0, stream>>>(
                Att_hi + (size_t)m0 * H, Att_lo + (size_t)m0 * H, Pss_hi, Pss_lo,
                H, Ns, Sss, nullptr, nullptr, nullptr);
            gemm_split3<0><<<dim3(Ne / 128, McF / 128), 256, 0, stream>>>(
                Att_hi + (size_t)m0 * H, Att_lo + (size_t)m0 * H, Pes_hi, Pes_lo,
                H, Ne, Ses, nullptr, nullptr, nullptr);
            softmax_row<8><<<McF, 256, 0, stream>>>(Sss, Wtss + (size_t)m0 * Ns);
            softmax_row<4><<<McF, 256, 0, stream>>>(Ses, Wtes + (size_t)m0 * Ne);
        }

        // stage 2b: full-M ctx GEMMs (grid 512 blocks each)
        gemm_f16<<<dim3(H / 128, M / 128), 256, 0, stream>>>(Wtss, Vtss, Ns, H, Ctxss);
        gemm_f16<<<dim3(H / 128, M / 128), 256, 0, stream>>>(Wtes, Vtes, Ne, H, Ctxes);

        // stage 3
        gemm_final<<<dim3(AO / 128, M / 128), 256, 0, stream>>>(
            Att_hi, Ctxss, Ctxes, Wl16, blin, Out);
        return;
    }

    // ---------------- fallback: chunked-ctx path (round-1 scheme) ----------------
    {
        size_t off2 = persist_end + ((sizeA + 255) & ~(size_t)255);
        auto carve2 = [&](size_t bytes) {
            char* r = base + off2;
            off2 = (off2 + bytes + 255) & ~(size_t)255;
            return r;
        };
        f16* Ctxss = (f16*)carve2((size_t)M * H * 2);
        f16* Ctxes = (f16*)carve2((size_t)M * H * 2);
        const size_t perRow = (size_t)Ns * 4 + (size_t)Ne * 4 + (size_t)Ns * 2 + (size_t)Ne * 2;
        int Mc = 2048;
        while (Mc > 128 && off2 + (size_t)Mc * perRow + 4096 > ws_size) Mc >>= 1;
        if (off2 + (size_t)Mc * perRow + 4096 > ws_size) return;  // ws too small: fail loudly
        float* Sss = (float*)carve2((size_t)Mc * Ns * 4);
        float* Ses = (float*)carve2((size_t)Mc * Ne * 4);
        f16* Wtss  = (f16*)carve2((size_t)Mc * Ns * 2);
        f16* Wtes  = (f16*)carve2((size_t)Mc * Ne * 2);

        split_f32_f16<<<(M * H) / 1024, 256, 0, stream>>>(Att, Att_hi, Att_lo);
        split_f32_f16<<<(Ns * H) / 1024, 256, 0, stream>>>(Xss, Xss_hi, Xss_lo);
        split_f32_f16<<<(Ne * H) / 1024, 256, 0, stream>>>(Xes, Xes_hi, Xes_lo);
        split_f32_f16<<<(H * H) / 1024, 256, 0, stream>>>(Wss, Wss_hi, Wss_lo);
        split_f32_f16<<<(H * H) / 1024, 256, 0, stream>>>(Wes, Wes_hi, Wes_lo);
        conv_f32_f16<<<(AO * K3) / 1024, 256, 0, stream>>>(Wlin, Wl16);
        transpose_f32_to_f16<<<dim3(Ns / 64, H / 64), 256, 0, stream>>>(Xss, Vtss, Ns, H);
        transpose_f32_to_f16<<<dim3(Ne / 64, H / 64), 256, 0, stream>>>(Xes, Vtes, Ne, H);

        gemm_split3<1><<<dim3(H / 128, Ns / 128), 256, 0, stream>>>(
            Xss_hi, Xss_lo, Wss_hi, Wss_lo, H, H, nullptr, Pss_hi, Pss_lo, bss);
        gemm_split3<1><<<dim3(H / 128, Ne / 128), 256, 0, stream>>>(
            Xes_hi, Xes_lo, Wes_hi, Wes_lo, H, H, nullptr, Pes_hi, Pes_lo, bes);

        for (int m0 = 0; m0 < M; m0 += Mc) {
            gemm_split3<0><<<dim3(Ns / 128, Mc / 128), 256, 0, stream>>>(
                Att_hi + (size_t)m0 * H, Att_lo + (size_t)m0 * H, Pss_hi, Pss_lo,
                H, Ns, Sss, nullptr, nullptr, nullptr);
            gemm_split3<0><<<dim3(Ne / 128, Mc / 128), 256, 0, stream>>>(
                Att_hi + (size_t)m0 * H, Att_lo + (size_t)m0 * H, Pes_hi, Pes_lo,
                H, Ne, Ses, nullptr, nullptr, nullptr);
            softmax_row<8><<<Mc, 256, 0, stream>>>(Sss, Wtss);
            softmax_row<4><<<Mc, 256, 0, stream>>>(Ses, Wtes);
            gemm_f16<<<dim3(H / 128, Mc / 128), 256, 0, stream>>>(Wtss, Vtss, Ns, H, Ctxss + (size_t)m0 * H);
            gemm_f16<<<dim3(H / 128, Mc / 128), 256, 0, stream>>>(Wtes, Vtes, Ne, H, Ctxes + (size_t)m0 * H);
        }

        gemm_final<<<dim3(AO / 128, M / 128), 256, 0, stream>>>(
            Att_hi, Ctxss, Ctxes, Wl16, blin, Out);
    }
}

// Round 3
// 1487.069 us; speedup vs baseline: 3.4758x; 3.4758x over previous
//
#include <hip/hip_runtime.h>
#include <hip/hip_fp16.h>
#include <stdint.h>

typedef _Float16 f16;
typedef _Float16 f16x8 __attribute__((ext_vector_type(8)));
typedef _Float16 f16x4 __attribute__((ext_vector_type(4)));
typedef float f32x4 __attribute__((ext_vector_type(4)));

#define DEV __device__ __forceinline__

DEV void gload_lds16(const void* g, void* l) {
    __builtin_amdgcn_global_load_lds(
        (const __attribute__((address_space(1))) void*)g,
        (__attribute__((address_space(3))) void*)l, 16, 0, 0);
}

// ---------------------------------------------------------------------------
// Score GEMM: S = (A_f32 split hi/lo) @ (Bhi+Blo)^T, K=1024 fixed.
// A: f32 [*,1024] (split to hi/lo fp16 during staging; drops lo*lo term)
// B: fp16 hi/lo pair [N,1024]. C: f32 [*,ldc].
// ---------------------------------------------------------------------------
__global__ __launch_bounds__(256, 2) void gemm_score(
    const float* __restrict__ A, const f16* __restrict__ Bhi,
    const f16* __restrict__ Blo, int ldc, float* __restrict__ S)
{
    __shared__ alignas(16) f16 As_hi[128 * 32];
    __shared__ alignas(16) f16 As_lo[128 * 32];
    __shared__ alignas(16) f16 Bs_hi[128 * 32];
    __shared__ alignas(16) f16 Bs_lo[128 * 32];
    const int t = threadIdx.x;
    const int lane = t & 63;
    const int w = t >> 6;
    const size_t m0 = (size_t)blockIdx.y * 128;
    const size_t n0 = (size_t)blockIdx.x * 128;
    const int wrow = (w >> 1) * 64;
    const int wcol = (w & 1) * 64;

    f32x4 acc[4][4] = {};

    for (int k0 = 0; k0 < 1024; k0 += 32) {
        __syncthreads();
        // A: reg-stage f32 -> hi/lo fp16 (4 passes x f32x4)
#pragma unroll
        for (int p = 0; p < 4; ++p) {
            const int idx = p * 256 + t;
            const int row = idx >> 3;
            const int col4 = (idx & 7) << 2;
            const f32x4 v = *(const f32x4*)&A[(m0 + row) * 1024 + k0 + col4];
            f16x4 h, l;
#pragma unroll
            for (int j = 0; j < 4; ++j) {
                h[j] = (f16)v[j];
                l[j] = (f16)(v[j] - (float)h[j]);
            }
            *(f16x4*)&As_hi[idx * 4] = h;
            *(f16x4*)&As_lo[idx * 4] = l;
        }
        // B: direct global->LDS (2 passes x 16B)
#pragma unroll
        for (int i = 0; i < 2; ++i) {
            const int c = i * 256 + t;
            const int row = c >> 2;
            const int col = (c & 3) << 3;
            const int loff = (i * 256 + w * 64) * 8;
            const size_t gb = (n0 + row) * (size_t)1024 + k0 + col;
            gload_lds16(Bhi + gb, &Bs_hi[loff]);
            gload_lds16(Blo + gb, &Bs_lo[loff]);
        }
        __syncthreads();
        const int fr = lane & 15;
        const int fk = (lane >> 4) << 3;
        f16x8 ah[4], al[4], bh[4], bl[4];
#pragma unroll
        for (int x = 0; x < 4; ++x) {
            ah[x] = *(const f16x8*)&As_hi[(wrow + x * 16 + fr) * 32 + fk];
            al[x] = *(const f16x8*)&As_lo[(wrow + x * 16 + fr) * 32 + fk];
            bh[x] = *(const f16x8*)&Bs_hi[(wcol + x * 16 + fr) * 32 + fk];
            bl[x] = *(const f16x8*)&Bs_lo[(wcol + x * 16 + fr) * 32 + fk];
        }
#pragma unroll
        for (int mi = 0; mi < 4; ++mi)
#pragma unroll
            for (int ni = 0; ni < 4; ++ni) {
                acc[mi][ni] = __builtin_amdgcn_mfma_f32_16x16x32_f16(ah[mi], bh[ni], acc[mi][ni], 0, 0, 0);
                acc[mi][ni] = __builtin_amdgcn_mfma_f32_16x16x32_f16(al[mi], bh[ni], acc[mi][ni], 0, 0, 0);
                acc[mi][ni] = __builtin_amdgcn_mfma_f32_16x16x32_f16(ah[mi], bl[ni], acc[mi][ni], 0, 0, 0);
            }
    }

    const int fr = lane & 15;
    const int fq = lane >> 4;
#pragma unroll
    for (int mi = 0; mi < 4; ++mi)
#pragma unroll
        for (int ni = 0; ni < 4; ++ni)
#pragma unroll
            for (int r = 0; r < 4; ++r) {
                const size_t row = m0 + wrow + mi * 16 + fq * 4 + r;
                const size_t col = n0 + wcol + ni * 16 + fr;
                S[row * (size_t)ldc + col] = acc[mi][ni][r];
            }
}

// ---------------------------------------------------------------------------
// Projection GEMM: P(hi,lo) = (A_f32 split) @ (B_f32 split)^T + bias, K=1024.
// A: f32 [N,1024], B: f32 [128-blocked rows, 1024]. Drops lo*lo.
// ---------------------------------------------------------------------------
__global__ __launch_bounds__(256, 2) void gemm_proj(
    const float* __restrict__ A, const float* __restrict__ B,
    const float* __restrict__ bias, int ldc,
    f16* __restrict__ Phi, f16* __restrict__ Plo)
{
    __shared__ alignas(16) f16 As_hi[128 * 32];
    __shared__ alignas(16) f16 As_lo[128 * 32];
    __shared__ alignas(16) f16 Bs_hi[128 * 32];
    __shared__ alignas(16) f16 Bs_lo[128 * 32];
    const int t = threadIdx.x;
    const int lane = t & 63;
    const int w = t >> 6;
    const size_t m0 = (size_t)blockIdx.y * 128;
    const size_t n0 = (size_t)blockIdx.x * 128;
    const int wrow = (w >> 1) * 64;
    const int wcol = (w & 1) * 64;

    f32x4 acc[4][4] = {};

    for (int k0 = 0; k0 < 1024; k0 += 32) {
        __syncthreads();
#pragma unroll
        for (int p = 0; p < 4; ++p) {
            const int idx = p * 256 + t;
            const int row = idx >> 3;
            const int col4 = (idx & 7) << 2;
            const f32x4 va = *(const f32x4*)&A[(m0 + row) * 1024 + k0 + col4];
            const f32x4 vb = *(const f32x4*)&B[(n0 + row) * 1024 + k0 + col4];
            f16x4 ha, la, hb, lb;
#pragma unroll
            for (int j = 0; j < 4; ++j) {
                ha[j] = (f16)va[j];
                la[j] = (f16)(va[j] - (float)ha[j]);
                hb[j] = (f16)vb[j];
                lb[j] = (f16)(vb[j] - (float)hb[j]);
            }
            *(f16x4*)&As_hi[idx * 4] = ha;
            *(f16x4*)&As_lo[idx * 4] = la;
            *(f16x4*)&Bs_hi[idx * 4] = hb;
            *(f16x4*)&Bs_lo[idx * 4] = lb;
        }
        __syncthreads();
        const int fr = lane & 15;
        const int fk = (lane >> 4) << 3;
        f16x8 ah[4], al[4], bh[4], bl[4];
#pragma unroll
        for (int x = 0; x < 4; ++x) {
            ah[x] = *(const f16x8*)&As_hi[(wrow + x * 16 + fr) * 32 + fk];
            al[x] = *(const f16x8*)&As_lo[(wrow + x * 16 + fr) * 32 + fk];
            bh[x] = *(const f16x8*)&Bs_hi[(wcol + x * 16 + fr) * 32 + fk];
            bl[x] = *(const f16x8*)&Bs_lo[(wcol + x * 16 + fr) * 32 + fk];
        }
#pragma unroll
        for (int mi = 0; mi < 4; ++mi)
#pragma unroll
            for (int ni = 0; ni < 4; ++ni) {
                acc[mi][ni] = __builtin_amdgcn_mfma_f32_16x16x32_f16(ah[mi], bh[ni], acc[mi][ni], 0, 0, 0);
                acc[mi][ni] = __builtin_amdgcn_mfma_f32_16x16x32_f16(al[mi], bh[ni], acc[mi][ni], 0, 0, 0);
                acc[mi][ni] = __builtin_amdgcn_mfma_f32_16x16x32_f16(ah[mi], bl[ni], acc[mi][ni], 0, 0, 0);
            }
    }

    const int fr = lane & 15;
    const int fq = lane >> 4;
#pragma unroll
    for (int mi = 0; mi < 4; ++mi)
#pragma unroll
        for (int ni = 0; ni < 4; ++ni)
#pragma unroll
            for (int r = 0; r < 4; ++r) {
                const size_t row = m0 + wrow + mi * 16 + fq * 4 + r;
                const size_t col = n0 + wcol + ni * 16 + fr;
                float v = acc[mi][ni][r] + bias[col];
                const f16 h = (f16)v;
                Phi[row * (size_t)ldc + col] = h;
                Plo[row * (size_t)ldc + col] = (f16)(v - (float)h);
            }
}

// ---------------------------------------------------------------------------
// Single fp16 GEMM: C(fp16) = A @ B^T. A:[M,K] B:[N,K], lda=ldb=K.
// ---------------------------------------------------------------------------
__global__ __launch_bounds__(256, 4) void gemm_f16(
    const f16* __restrict__ A, const f16* __restrict__ B,
    int K, int ldc, f16* __restrict__ C)
{
    __shared__ alignas(16) f16 As[128 * 32];
    __shared__ alignas(16) f16 Bs[128 * 32];
    const int t = threadIdx.x;
    const int lane = t & 63;
    const int w = t >> 6;
    const size_t m0 = (size_t)blockIdx.y * 128;
    const size_t n0 = (size_t)blockIdx.x * 128;
    const int wrow = (w >> 1) * 64;
    const int wcol = (w & 1) * 64;

    f32x4 acc[4][4] = {};

    for (int k0 = 0; k0 < K; k0 += 32) {
        __syncthreads();
#pragma unroll
        for (int i = 0; i < 2; ++i) {
            const int c = i * 256 + t;
            const int row = c >> 2;
            const int col = (c & 3) << 3;
            const int loff = (i * 256 + w * 64) * 8;
            gload_lds16(A + (m0 + row) * (size_t)K + k0 + col, &As[loff]);
            gload_lds16(B + (n0 + row) * (size_t)K + k0 + col, &Bs[loff]);
        }
        __syncthreads();
        const int fr = lane & 15;
        const int fk = (lane >> 4) << 3;
        f16x8 a[4], b[4];
#pragma unroll
        for (int x = 0; x < 4; ++x) {
            a[x] = *(const f16x8*)&As[(wrow + x * 16 + fr) * 32 + fk];
            b[x] = *(const f16x8*)&Bs[(wcol + x * 16 + fr) * 32 + fk];
        }
#pragma unroll
        for (int mi = 0; mi < 4; ++mi)
#pragma unroll
            for (int ni = 0; ni < 4; ++ni)
                acc[mi][ni] = __builtin_amdgcn_mfma_f32_16x16x32_f16(a[mi], b[ni], acc[mi][ni], 0, 0, 0);
    }

    const int fr = lane & 15;
    const int fq = lane >> 4;
#pragma unroll
    for (int mi = 0; mi < 4; ++mi)
#pragma unroll
        for (int ni = 0; ni < 4; ++ni)
#pragma unroll
            for (int r = 0; r < 4; ++r) {
                const size_t row = m0 + wrow + mi * 16 + fq * 4 + r;
                const size_t col = n0 + wcol + ni * 16 + fr;
                C[row * (size_t)ldc + col] = (f16)acc[mi][ni][r];
            }
}

// ---------------------------------------------------------------------------
// Final GEMM: Out = tanh(cat @ B^T + bias). cat = [Att(f32, conv in-kernel),
// ctx_ss(f16), ctx_es(f16)], each K-segment 1024. B = Wlin fp16 [1024,3072].
// ---------------------------------------------------------------------------
__global__ __launch_bounds__(256, 2) void gemm_final(
    const float* __restrict__ A0, const f16* __restrict__ A1,
    const f16* __restrict__ A2, const f16* __restrict__ B,
    const float* __restrict__ bias, float* __restrict__ Out)
{
    __shared__ alignas(16) f16 As[128 * 32];
    __shared__ alignas(16) f16 Bs[128 * 32];
    const int t = threadIdx.x;
    const int lane = t & 63;
    const int w = t >> 6;
    const size_t m0 = (size_t)blockIdx.y * 128;
    const size_t n0 = (size_t)blockIdx.x * 128;
    const int wrow = (w >> 1) * 64;
    const int wcol = (w & 1) * 64;
    const int K = 3072;

    f32x4 acc[4][4] = {};

    for (int k0 = 0; k0 < K; k0 += 32) {
        const int kl = k0 & 1023;
        __syncthreads();
        if (k0 < 1024) {
            // f32 segment: reg-stage + convert
#pragma unroll
            for (int p = 0; p < 4; ++p) {
                const int idx = p * 256 + t;
                const int row = idx >> 3;
                const int col4 = (idx & 7) << 2;
                const f32x4 v = *(const f32x4*)&A0[(m0 + row) * 1024 + kl + col4];
                f16x4 h;
#pragma unroll
                for (int j = 0; j < 4; ++j) h[j] = (f16)v[j];
                *(f16x4*)&As[idx * 4] = h;
            }
        } else {
            const f16* Aseg = (k0 < 2048) ? A1 : A2;
#pragma unroll
            for (int i = 0; i < 2; ++i) {
                const int c = i * 256 + t;
                const int row = c >> 2;
                const int col = (c & 3) << 3;
                const int loff = (i * 256 + w * 64) * 8;
                gload_lds16(Aseg + (m0 + row) * (size_t)1024 + kl + col, &As[loff]);
            }
        }
#pragma unroll
        for (int i = 0; i < 2; ++i) {
            const int c = i * 256 + t;
            const int row = c >> 2;
            const int col = (c & 3) << 3;
            const int loff = (i * 256 + w * 64) * 8;
            gload_lds16(B + (n0 + row) * (size_t)K + k0 + col, &Bs[loff]);
        }
        __syncthreads();
        const int fr = lane & 15;
        const int fk = (lane >> 4) << 3;
        f16x8 a[4], b[4];
#pragma unroll
        for (int x = 0; x < 4; ++x) {
            a[x] = *(const f16x8*)&As[(wrow + x * 16 + fr) * 32 + fk];
            b[x] = *(const f16x8*)&Bs[(wcol + x * 16 + fr) * 32 + fk];
        }
#pragma unroll
        for (int mi = 0; mi < 4; ++mi)
#pragma unroll
            for (int ni = 0; ni < 4; ++ni)
                acc[mi][ni] = __builtin_amdgcn_mfma_f32_16x16x32_f16(a[mi], b[ni], acc[mi][ni], 0, 0, 0);
    }

    const int fr = lane & 15;
    const int fq = lane >> 4;
#pragma unroll
    for (int mi = 0; mi < 4; ++mi)
#pragma unroll
        for (int ni = 0; ni < 4; ++ni)
#pragma unroll
            for (int r = 0; r < 4; ++r) {
                const size_t row = m0 + wrow + mi * 16 + fq * 4 + r;
                const size_t col = n0 + wcol + ni * 16 + fr;
                Out[row * 1024 + col] = tanhf(acc[mi][ni][r] + bias[col]);
            }
}

// ---------------------------------------------------------------------------
// Row softmax: one block per row of length C*1024 f32 -> fp16 weights.
// ---------------------------------------------------------------------------
template <int C>
__global__ __launch_bounds__(256) void softmax_row(
    const float* __restrict__ S, f16* __restrict__ W)
{
    const float* s = S + (size_t)blockIdx.x * (C * 1024);
    f16* w = W + (size_t)blockIdx.x * (C * 1024);
    const int t = threadIdx.x;
    f32x4 v[C];
    float mx = -3.0e38f;
#pragma unroll
    for (int i = 0; i < C; ++i) {
        v[i] = *(const f32x4*)&s[(t + i * 256) * 4];
        mx = fmaxf(mx, fmaxf(fmaxf(v[i][0], v[i][1]), fmaxf(v[i][2], v[i][3])));
    }
#pragma unroll
    for (int off = 32; off; off >>= 1) mx = fmaxf(mx, __shfl_xor(mx, off));
    __shared__ float red[8];
    if ((t & 63) == 0) red[t >> 6] = mx;
    __syncthreads();
    mx = fmaxf(fmaxf(red[0], red[1]), fmaxf(red[2], red[3]));
    float sm = 0.f;
#pragma unroll
    for (int i = 0; i < C; ++i) {
        v[i][0] = __expf(v[i][0] - mx);
        v[i][1] = __expf(v[i][1] - mx);
        v[i][2] = __expf(v[i][2] - mx);
        v[i][3] = __expf(v[i][3] - mx);
        sm += (v[i][0] + v[i][1]) + (v[i][2] + v[i][3]);
    }
#pragma unroll
    for (int off = 32; off; off >>= 1) sm += __shfl_xor(sm, off);
    if ((t & 63) == 0) red[4 + (t >> 6)] = sm;
    __syncthreads();
    sm = (red[4] + red[5]) + (red[6] + red[7]);
    const float inv = 1.f / sm;
#pragma unroll
    for (int i = 0; i < C; ++i) {
        f16x4 o;
        o[0] = (f16)(v[i][0] * inv);
        o[1] = (f16)(v[i][1] * inv);
        o[2] = (f16)(v[i][2] * inv);
        o[3] = (f16)(v[i][3] * inv);
        *(f16x4*)&w[(t + i * 256) * 4] = o;
    }
}

// ---------------------------------------------------------------------------
// Transpose X[N,H] f32 -> Xt[H,N] fp16 (64x64 tiles via LDS)
// ---------------------------------------------------------------------------
__global__ __launch_bounds__(256) void transpose_f32_to_f16(
    const float* __restrict__ X, f16* __restrict__ Xt, int N, int H)
{
    __shared__ float tile[64][65];
    const int n0 = blockIdx.x * 64;
    const int h0 = blockIdx.y * 64;
    const int tx = threadIdx.x & 15;
    const int ty = threadIdx.x >> 4;
#pragma unroll
    for (int i = 0; i < 4; ++i) {
        const int r = ty + i * 16;
        const f32x4 vv = *(const f32x4*)&X[(size_t)(n0 + r) * H + h0 + tx * 4];
        tile[r][tx * 4 + 0] = vv[0];
        tile[r][tx * 4 + 1] = vv[1];
        tile[r][tx * 4 + 2] = vv[2];
        tile[r][tx * 4 + 3] = vv[3];
    }
    __syncthreads();
#pragma unroll
    for (int i = 0; i < 4; ++i) {
        const int hh = ty + i * 16;
        f16x4 o;
        o[0] = (f16)tile[tx * 4 + 0][hh];
        o[1] = (f16)tile[tx * 4 + 1][hh];
        o[2] = (f16)tile[tx * 4 + 2][hh];
        o[3] = (f16)tile[tx * 4 + 3][hh];
        *(f16x4*)&Xt[(size_t)(h0 + hh) * N + n0 + tx * 4] = o;
    }
}

__global__ __launch_bounds__(256) void conv_f32_f16(
    const float* __restrict__ X, f16* __restrict__ Y)
{
    const size_t i = ((size_t)blockIdx.x * 256 + threadIdx.x) * 4;
    const f32x4 v = *(const f32x4*)&X[i];
    f16x4 h;
#pragma unroll
    for (int j = 0; j < 4; ++j) h[j] = (f16)v[j];
    *(f16x4*)&Y[i] = h;
}

// ---------------------------------------------------------------------------
extern "C" void kernel_launch(void* const* d_in, const int* in_sizes, int n_in,
                              void* d_out, int out_size, void* d_ws, size_t ws_size,
                              hipStream_t stream)
{
    (void)in_sizes; (void)n_in; (void)out_size;
    constexpr int Ns = 8192, Ne = 4096, M = 8192, H = 1024, K3 = 3072, AO = 1024;

    const float* Xss  = (const float*)d_in[0];
    const float* Xes  = (const float*)d_in[1];
    const float* Att  = (const float*)d_in[2];
    const float* Wss  = (const float*)d_in[3];
    const float* bss  = (const float*)d_in[4];
    const float* Wes  = (const float*)d_in[5];
    const float* bes  = (const float*)d_in[6];
    const float* Wlin = (const float*)d_in[7];
    const float* blin = (const float*)d_in[8];
    float* Out = (float*)d_out;

    // ---- workspace layout (static ~216 MB + S chunk) ----
    char* base = (char*)d_ws;
    size_t off = 0;
    auto carve = [&](size_t bytes) {
        char* r = base + off;
        off = (off + bytes + 255) & ~(size_t)255;
        return r;
    };

    f16* Wl16   = (f16*)carve((size_t)AO * K3 * 2);            //  6.3 MB
    f16* Vtes   = (f16*)carve((size_t)H * Ne * 2);             //  8.4 MB
    f16* Vtss   = (f16*)carve((size_t)H * Ns * 2);             // 16.8 MB
    f16* Pes_hi = (f16*)carve((size_t)Ne * H * 2);             //  8.4 MB
    f16* Pes_lo = (f16*)carve((size_t)Ne * H * 2);             //  8.4 MB
    char* PssRg = carve((size_t)2 * Ns * H * 2);               // 33.6 MB (Pss hi/lo -> later Ctxss/Ctxes)
    f16* Pss_hi = (f16*)PssRg;
    f16* Pss_lo = Pss_hi + (size_t)Ns * H;
    char* WtRg  = carve((size_t)M * Ns * 2);                   // 134.2 MB (Wtss -> later Wtes)
    f16* Wtss   = (f16*)WtRg;
    f16* Wtes   = (f16*)WtRg;

    // S chunk takes the remainder
    size_t remain = (ws_size > off) ? ws_size - off : 0;
    int Mc = (int)(remain / ((size_t)Ns * 4));
    Mc = (Mc / 128) * 128;
    if (Mc > M) Mc = M;
    if (Mc < 128) return;  // ws too small: fail loudly (known ws >= 245 MB -> Mc >= 768)
    float* S = (float*)carve((size_t)Mc * Ns * 4);

    // Ctx aliased over Pss region (dead after ss scores complete)
    f16* Ctxss = (f16*)PssRg;
    f16* Ctxes = Ctxss + (size_t)M * H;

    // ---- stage 0: light conversions ----
    conv_f32_f16<<<(AO * K3) / 1024, 256, 0, stream>>>(Wlin, Wl16);
    transpose_f32_to_f16<<<dim3(Ns / 64, H / 64), 256, 0, stream>>>(Xss, Vtss, Ns, H);
    transpose_f32_to_f16<<<dim3(Ne / 64, H / 64), 256, 0, stream>>>(Xes, Vtes, Ne, H);

    // ---- stage 1: projections P = X @ W^T + b (in-kernel split) ----
    gemm_proj<<<dim3(H / 128, Ns / 128), 256, 0, stream>>>(Xss, Wss, bss, H, Pss_hi, Pss_lo);
    gemm_proj<<<dim3(H / 128, Ne / 128), 256, 0, stream>>>(Xes, Wes, bes, H, Pes_hi, Pes_lo);

    // ---- stage 2 (ss): scores -> softmax -> full weight matrix -> ctx ----
    for (int m0 = 0; m0 < M; m0 += Mc) {
        const int mc = (M - m0 < Mc) ? (M - m0) : Mc;
        gemm_score<<<dim3(Ns / 128, mc / 128), 256, 0, stream>>>(
            Att + (size_t)m0 * H, Pss_hi, Pss_lo, Ns, S);
        softmax_row<8><<<mc, 256, 0, stream>>>(S, Wtss + (size_t)m0 * Ns);
    }
    gemm_f16<<<dim3(H / 128, M / 128), 256, 0, stream>>>(Wtss, Vtss, Ns, H, Ctxss);

    // ---- stage 2 (es): same, reusing Wt region and S ----
    for (int m0 = 0; m0 < M; m0 += Mc) {
        const int mc = (M - m0 < Mc) ? (M - m0) : Mc;
        gemm_score<<<dim3(Ne / 128, mc / 128), 256, 0, stream>>>(
            Att + (size_t)m0 * H, Pes_hi, Pes_lo, Ne, S);
        softmax_row<4><<<mc, 256, 0, stream>>>(S, Wtes + (size_t)m0 * Ne);
    }
    gemm_f16<<<dim3(H / 128, M / 128), 256, 0, stream>>>(Wtes, Vtes, Ne, H, Ctxes);

    // ---- stage 3: out = tanh([att, ctx_ss, ctx_es] @ Wlin^T + b) ----
    gemm_final<<<dim3(AO / 128, M / 128), 256, 0, stream>>>(
        Att, Ctxss, Ctxes, Wl16, blin, Out);
}

// Round 4
// 1411.074 us; speedup vs baseline: 3.6630x; 1.0539x over previous
//
#include <hip/hip_runtime.h>
#include <hip/hip_fp16.h>
#include <stdint.h>

typedef _Float16 f16;
typedef _Float16 f16x8 __attribute__((ext_vector_type(8)));
typedef _Float16 f16x4 __attribute__((ext_vector_type(4)));
typedef float f32x4 __attribute__((ext_vector_type(4)));

#define DEV __device__ __forceinline__

DEV void gload_lds16(const void* g, void* l) {
    __builtin_amdgcn_global_load_lds(
        (const __attribute__((address_space(1))) void*)g,
        (__attribute__((address_space(3))) void*)l, 16, 0, 0);
}

// XCD panel-grouped swizzle: all nx n-tiles of an m-panel land on one XCD.
// Requires ny % 8 == 0 and grid = nx*ny (1-D).
DEV void swz_map(int bid, int nx, int ny, int& bm, int& bn) {
    const int xcd = bid & 7;
    const int j = bid >> 3;          // 0 .. nx*ny/8 - 1
    const int py = ny >> 3;          // panels per XCD
    bm = xcd * py + j / nx;
    bn = j % nx;
}

// ---------------------------------------------------------------------------
// Score GEMM: S = (A_f32 split hi/lo) @ (Bhi+Blo)^T, K=1024 fixed.
// A: f32 [*,1024] (split to hi/lo fp16 during staging; drops lo*lo term)
// B: fp16 hi/lo pair [N,1024]. C: f32 [*,ldc].
// ---------------------------------------------------------------------------
__global__ __launch_bounds__(256, 2) void gemm_score(
    const float* __restrict__ A, const f16* __restrict__ Bhi,
    const f16* __restrict__ Blo, int ldc, float* __restrict__ S)
{
    __shared__ alignas(16) f16 As_hi[128 * 32];
    __shared__ alignas(16) f16 As_lo[128 * 32];
    __shared__ alignas(16) f16 Bs_hi[128 * 32];
    __shared__ alignas(16) f16 Bs_lo[128 * 32];
    const int t = threadIdx.x;
    const int lane = t & 63;
    const int w = t >> 6;
    const size_t m0 = (size_t)blockIdx.y * 128;
    const size_t n0 = (size_t)blockIdx.x * 128;
    const int wrow = (w >> 1) * 64;
    const int wcol = (w & 1) * 64;

    f32x4 acc[4][4] = {};

    for (int k0 = 0; k0 < 1024; k0 += 32) {
        __syncthreads();
        // A: reg-stage f32 -> hi/lo fp16 (4 passes x f32x4)
#pragma unroll
        for (int p = 0; p < 4; ++p) {
            const int idx = p * 256 + t;
            const int row = idx >> 3;
            const int col4 = (idx & 7) << 2;
            const f32x4 v = *(const f32x4*)&A[(m0 + row) * 1024 + k0 + col4];
            f16x4 h, l;
#pragma unroll
            for (int j = 0; j < 4; ++j) {
                h[j] = (f16)v[j];
                l[j] = (f16)(v[j] - (float)h[j]);
            }
            *(f16x4*)&As_hi[idx * 4] = h;
            *(f16x4*)&As_lo[idx * 4] = l;
        }
        // B: direct global->LDS (2 passes x 16B)
#pragma unroll
        for (int i = 0; i < 2; ++i) {
            const int c = i * 256 + t;
            const int row = c >> 2;
            const int col = (c & 3) << 3;
            const int loff = (i * 256 + w * 64) * 8;
            const size_t gb = (n0 + row) * (size_t)1024 + k0 + col;
            gload_lds16(Bhi + gb, &Bs_hi[loff]);
            gload_lds16(Blo + gb, &Bs_lo[loff]);
        }
        __syncthreads();
        const int fr = lane & 15;
        const int fk = (lane >> 4) << 3;
        f16x8 ah[4], al[4], bh[4], bl[4];
#pragma unroll
        for (int x = 0; x < 4; ++x) {
            ah[x] = *(const f16x8*)&As_hi[(wrow + x * 16 + fr) * 32 + fk];
            al[x] = *(const f16x8*)&As_lo[(wrow + x * 16 + fr) * 32 + fk];
            bh[x] = *(const f16x8*)&Bs_hi[(wcol + x * 16 + fr) * 32 + fk];
            bl[x] = *(const f16x8*)&Bs_lo[(wcol + x * 16 + fr) * 32 + fk];
        }
#pragma unroll
        for (int mi = 0; mi < 4; ++mi)
#pragma unroll
            for (int ni = 0; ni < 4; ++ni) {
                acc[mi][ni] = __builtin_amdgcn_mfma_f32_16x16x32_f16(ah[mi], bh[ni], acc[mi][ni], 0, 0, 0);
                acc[mi][ni] = __builtin_amdgcn_mfma_f32_16x16x32_f16(al[mi], bh[ni], acc[mi][ni], 0, 0, 0);
                acc[mi][ni] = __builtin_amdgcn_mfma_f32_16x16x32_f16(ah[mi], bl[ni], acc[mi][ni], 0, 0, 0);
            }
    }

    const int fr = lane & 15;
    const int fq = lane >> 4;
#pragma unroll
    for (int mi = 0; mi < 4; ++mi)
#pragma unroll
        for (int ni = 0; ni < 4; ++ni)
#pragma unroll
            for (int r = 0; r < 4; ++r) {
                const size_t row = m0 + wrow + mi * 16 + fq * 4 + r;
                const size_t col = n0 + wcol + ni * 16 + fr;
                S[row * (size_t)ldc + col] = acc[mi][ni][r];
            }
}

// ---------------------------------------------------------------------------
// Projection GEMM: P(hi,lo) = (A_f32 split) @ (B_f32 split)^T + bias, K=1024.
// ---------------------------------------------------------------------------
__global__ __launch_bounds__(256, 2) void gemm_proj(
    const float* __restrict__ A, const float* __restrict__ B,
    const float* __restrict__ bias, int ldc,
    f16* __restrict__ Phi, f16* __restrict__ Plo)
{
    __shared__ alignas(16) f16 As_hi[128 * 32];
    __shared__ alignas(16) f16 As_lo[128 * 32];
    __shared__ alignas(16) f16 Bs_hi[128 * 32];
    __shared__ alignas(16) f16 Bs_lo[128 * 32];
    const int t = threadIdx.x;
    const int lane = t & 63;
    const int w = t >> 6;
    const size_t m0 = (size_t)blockIdx.y * 128;
    const size_t n0 = (size_t)blockIdx.x * 128;
    const int wrow = (w >> 1) * 64;
    const int wcol = (w & 1) * 64;

    f32x4 acc[4][4] = {};

    for (int k0 = 0; k0 < 1024; k0 += 32) {
        __syncthreads();
#pragma unroll
        for (int p = 0; p < 4; ++p) {
            const int idx = p * 256 + t;
            const int row = idx >> 3;
            const int col4 = (idx & 7) << 2;
            const f32x4 va = *(const f32x4*)&A[(m0 + row) * 1024 + k0 + col4];
            const f32x4 vb = *(const f32x4*)&B[(n0 + row) * 1024 + k0 + col4];
            f16x4 ha, la, hb, lb;
#pragma unroll
            for (int j = 0; j < 4; ++j) {
                ha[j] = (f16)va[j];
                la[j] = (f16)(va[j] - (float)ha[j]);
                hb[j] = (f16)vb[j];
                lb[j] = (f16)(vb[j] - (float)hb[j]);
            }
            *(f16x4*)&As_hi[idx * 4] = ha;
            *(f16x4*)&As_lo[idx * 4] = la;
            *(f16x4*)&Bs_hi[idx * 4] = hb;
            *(f16x4*)&Bs_lo[idx * 4] = lb;
        }
        __syncthreads();
        const int fr = lane & 15;
        const int fk = (lane >> 4) << 3;
        f16x8 ah[4], al[4], bh[4], bl[4];
#pragma unroll
        for (int x = 0; x < 4; ++x) {
            ah[x] = *(const f16x8*)&As_hi[(wrow + x * 16 + fr) * 32 + fk];
            al[x] = *(const f16x8*)&As_lo[(wrow + x * 16 + fr) * 32 + fk];
            bh[x] = *(const f16x8*)&Bs_hi[(wcol + x * 16 + fr) * 32 + fk];
            bl[x] = *(const f16x8*)&Bs_lo[(wcol + x * 16 + fr) * 32 + fk];
        }
#pragma unroll
        for (int mi = 0; mi < 4; ++mi)
#pragma unroll
            for (int ni = 0; ni < 4; ++ni) {
                acc[mi][ni] = __builtin_amdgcn_mfma_f32_16x16x32_f16(ah[mi], bh[ni], acc[mi][ni], 0, 0, 0);
                acc[mi][ni] = __builtin_amdgcn_mfma_f32_16x16x32_f16(al[mi], bh[ni], acc[mi][ni], 0, 0, 0);
                acc[mi][ni] = __builtin_amdgcn_mfma_f32_16x16x32_f16(ah[mi], bl[ni], acc[mi][ni], 0, 0, 0);
            }
    }

    const int fr = lane & 15;
    const int fq = lane >> 4;
#pragma unroll
    for (int mi = 0; mi < 4; ++mi)
#pragma unroll
        for (int ni = 0; ni < 4; ++ni)
#pragma unroll
            for (int r = 0; r < 4; ++r) {
                const size_t row = m0 + wrow + mi * 16 + fq * 4 + r;
                const size_t col = n0 + wcol + ni * 16 + fr;
                float v = acc[mi][ni][r] + bias[col];
                const f16 h = (f16)v;
                Phi[row * (size_t)ldc + col] = h;
                Plo[row * (size_t)ldc + col] = (f16)(v - (float)h);
            }
}

// ---------------------------------------------------------------------------
// Single fp16 GEMM with XCD panel-grouped swizzle (1-D grid = nx*ny).
// C(fp16) = A @ B^T. A:[ny*128,K] B:[nx*128,K].
// ---------------------------------------------------------------------------
__global__ __launch_bounds__(256, 4) void gemm_f16(
    const f16* __restrict__ A, const f16* __restrict__ B,
    int K, int ldc, f16* __restrict__ C, int nx, int ny)
{
    __shared__ alignas(16) f16 As[128 * 32];
    __shared__ alignas(16) f16 Bs[128 * 32];
    const int t = threadIdx.x;
    const int lane = t & 63;
    const int w = t >> 6;
    int bm, bn;
    swz_map(blockIdx.x, nx, ny, bm, bn);
    const size_t m0 = (size_t)bm * 128;
    const size_t n0 = (size_t)bn * 128;
    const int wrow = (w >> 1) * 64;
    const int wcol = (w & 1) * 64;

    f32x4 acc[4][4] = {};

    for (int k0 = 0; k0 < K; k0 += 32) {
        __syncthreads();
#pragma unroll
        for (int i = 0; i < 2; ++i) {
            const int c = i * 256 + t;
            const int row = c >> 2;
            const int col = (c & 3) << 3;
            const int loff = (i * 256 + w * 64) * 8;
            gload_lds16(A + (m0 + row) * (size_t)K + k0 + col, &As[loff]);
            gload_lds16(B + (n0 + row) * (size_t)K + k0 + col, &Bs[loff]);
        }
        __syncthreads();
        const int fr = lane & 15;
        const int fk = (lane >> 4) << 3;
        f16x8 a[4], b[4];
#pragma unroll
        for (int x = 0; x < 4; ++x) {
            a[x] = *(const f16x8*)&As[(wrow + x * 16 + fr) * 32 + fk];
            b[x] = *(const f16x8*)&Bs[(wcol + x * 16 + fr) * 32 + fk];
        }
#pragma unroll
        for (int mi = 0; mi < 4; ++mi)
#pragma unroll
            for (int ni = 0; ni < 4; ++ni)
                acc[mi][ni] = __builtin_amdgcn_mfma_f32_16x16x32_f16(a[mi], b[ni], acc[mi][ni], 0, 0, 0);
    }

    const int fr = lane & 15;
    const int fq = lane >> 4;
#pragma unroll
    for (int mi = 0; mi < 4; ++mi)
#pragma unroll
        for (int ni = 0; ni < 4; ++ni)
#pragma unroll
            for (int r = 0; r < 4; ++r) {
                const size_t row = m0 + wrow + mi * 16 + fq * 4 + r;
                const size_t col = n0 + wcol + ni * 16 + fr;
                C[row * (size_t)ldc + col] = (f16)acc[mi][ni][r];
            }
}

// ---------------------------------------------------------------------------
// Final GEMM (swizzled): Out = tanh(cat @ B^T + bias). cat = [Att(f32,
// conv in-kernel), ctx_ss(f16), ctx_es(f16)]. B = Wlin fp16 [1024,3072].
// Grid 1-D 512 = 8 n-tiles x 64 m-panels.
// ---------------------------------------------------------------------------
__global__ __launch_bounds__(256, 2) void gemm_final(
    const float* __restrict__ A0, const f16* __restrict__ A1,
    const f16* __restrict__ A2, const f16* __restrict__ B,
    const float* __restrict__ bias, float* __restrict__ Out)
{
    __shared__ alignas(16) f16 As[128 * 32];
    __shared__ alignas(16) f16 Bs[128 * 32];
    const int t = threadIdx.x;
    const int lane = t & 63;
    const int w = t >> 6;
    int bm, bn;
    swz_map(blockIdx.x, 8, 64, bm, bn);
    const size_t m0 = (size_t)bm * 128;
    const size_t n0 = (size_t)bn * 128;
    const int wrow = (w >> 1) * 64;
    const int wcol = (w & 1) * 64;
    const int K = 3072;

    f32x4 acc[4][4] = {};

    for (int k0 = 0; k0 < K; k0 += 32) {
        const int kl = k0 & 1023;
        __syncthreads();
        if (k0 < 1024) {
#pragma unroll
            for (int p = 0; p < 4; ++p) {
                const int idx = p * 256 + t;
                const int row = idx >> 3;
                const int col4 = (idx & 7) << 2;
                const f32x4 v = *(const f32x4*)&A0[(m0 + row) * 1024 + kl + col4];
                f16x4 h;
#pragma unroll
                for (int j = 0; j < 4; ++j) h[j] = (f16)v[j];
                *(f16x4*)&As[idx * 4] = h;
            }
        } else {
            const f16* Aseg = (k0 < 2048) ? A1 : A2;
#pragma unroll
            for (int i = 0; i < 2; ++i) {
                const int c = i * 256 + t;
                const int row = c >> 2;
                const int col = (c & 3) << 3;
                const int loff = (i * 256 + w * 64) * 8;
                gload_lds16(Aseg + (m0 + row) * (size_t)1024 + kl + col, &As[loff]);
            }
        }
#pragma unroll
        for (int i = 0; i < 2; ++i) {
            const int c = i * 256 + t;
            const int row = c >> 2;
            const int col = (c & 3) << 3;
            const int loff = (i * 256 + w * 64) * 8;
            gload_lds16(B + (n0 + row) * (size_t)K + k0 + col, &Bs[loff]);
        }
        __syncthreads();
        const int fr = lane & 15;
        const int fk = (lane >> 4) << 3;
        f16x8 a[4], b[4];
#pragma unroll
        for (int x = 0; x < 4; ++x) {
            a[x] = *(const f16x8*)&As[(wrow + x * 16 + fr) * 32 + fk];
            b[x] = *(const f16x8*)&Bs[(wcol + x * 16 + fr) * 32 + fk];
        }
#pragma unroll
        for (int mi = 0; mi < 4; ++mi)
#pragma unroll
            for (int ni = 0; ni < 4; ++ni)
                acc[mi][ni] = __builtin_amdgcn_mfma_f32_16x16x32_f16(a[mi], b[ni], acc[mi][ni], 0, 0, 0);
    }

    const int fr = lane & 15;
    const int fq = lane >> 4;
#pragma unroll
    for (int mi = 0; mi < 4; ++mi)
#pragma unroll
        for (int ni = 0; ni < 4; ++ni)
#pragma unroll
            for (int r = 0; r < 4; ++r) {
                const size_t row = m0 + wrow + mi * 16 + fq * 4 + r;
                const size_t col = n0 + wcol + ni * 16 + fr;
                Out[row * 1024 + col] = tanhf(acc[mi][ni][r] + bias[col]);
            }
}

// ---------------------------------------------------------------------------
// Row softmax: one block per row of length C*1024 f32 -> fp16 weights.
// ---------------------------------------------------------------------------
template <int C>
__global__ __launch_bounds__(256) void softmax_row(
    const float* __restrict__ S, f16* __restrict__ W)
{
    const float* s = S + (size_t)blockIdx.x * (C * 1024);
    f16* w = W + (size_t)blockIdx.x * (C * 1024);
    const int t = threadIdx.x;
    f32x4 v[C];
    float mx = -3.0e38f;
#pragma unroll
    for (int i = 0; i < C; ++i) {
        v[i] = *(const f32x4*)&s[(t + i * 256) * 4];
        mx = fmaxf(mx, fmaxf(fmaxf(v[i][0], v[i][1]), fmaxf(v[i][2], v[i][3])));
    }
#pragma unroll
    for (int off = 32; off; off >>= 1) mx = fmaxf(mx, __shfl_xor(mx, off));
    __shared__ float red[8];
    if ((t & 63) == 0) red[t >> 6] = mx;
    __syncthreads();
    mx = fmaxf(fmaxf(red[0], red[1]), fmaxf(red[2], red[3]));
    float sm = 0.f;
#pragma unroll
    for (int i = 0; i < C; ++i) {
        v[i][0] = __expf(v[i][0] - mx);
        v[i][1] = __expf(v[i][1] - mx);
        v[i][2] = __expf(v[i][2] - mx);
        v[i][3] = __expf(v[i][3] - mx);
        sm += (v[i][0] + v[i][1]) + (v[i][2] + v[i][3]);
    }
#pragma unroll
    for (int off = 32; off; off >>= 1) sm += __shfl_xor(sm, off);
    if ((t & 63) == 0) red[4 + (t >> 6)] = sm;
    __syncthreads();
    sm = (red[4] + red[5]) + (red[6] + red[7]);
    const float inv = 1.f / sm;
#pragma unroll
    for (int i = 0; i < C; ++i) {
        f16x4 o;
        o[0] = (f16)(v[i][0] * inv);
        o[1] = (f16)(v[i][1] * inv);
        o[2] = (f16)(v[i][2] * inv);
        o[3] = (f16)(v[i][3] * inv);
        *(f16x4*)&w[(t + i * 256) * 4] = o;
    }
}

// ---------------------------------------------------------------------------
// Transpose X[N,H] f32 -> Xt[H,N] fp16 (64x64 tiles via LDS)
// ---------------------------------------------------------------------------
__global__ __launch_bounds__(256) void transpose_f32_to_f16(
    const float* __restrict__ X, f16* __restrict__ Xt, int N, int H)
{
    __shared__ float tile[64][65];
    const int n0 = blockIdx.x * 64;
    const int h0 = blockIdx.y * 64;
    const int tx = threadIdx.x & 15;
    const int ty = threadIdx.x >> 4;
#pragma unroll
    for (int i = 0; i < 4; ++i) {
        const int r = ty + i * 16;
        const f32x4 vv = *(const f32x4*)&X[(size_t)(n0 + r) * H + h0 + tx * 4];
        tile[r][tx * 4 + 0] = vv[0];
        tile[r][tx * 4 + 1] = vv[1];
        tile[r][tx * 4 + 2] = vv[2];
        tile[r][tx * 4 + 3] = vv[3];
    }
    __syncthreads();
#pragma unroll
    for (int i = 0; i < 4; ++i) {
        const int hh = ty + i * 16;
        f16x4 o;
        o[0] = (f16)tile[tx * 4 + 0][hh];
        o[1] = (f16)tile[tx * 4 + 1][hh];
        o[2] = (f16)tile[tx * 4 + 2][hh];
        o[3] = (f16)tile[tx * 4 + 3][hh];
        *(f16x4*)&Xt[(size_t)(h0 + hh) * N + n0 + tx * 4] = o;
    }
}

__global__ __launch_bounds__(256) void conv_f32_f16(
    const float* __restrict__ X, f16* __restrict__ Y)
{
    const size_t i = ((size_t)blockIdx.x * 256 + threadIdx.x) * 4;
    const f32x4 v = *(const f32x4*)&X[i];
    f16x4 h;
#pragma unroll
    for (int j = 0; j < 4; ++j) h[j] = (f16)v[j];
    *(f16x4*)&Y[i] = h;
}

// ---------------------------------------------------------------------------
extern "C" void kernel_launch(void* const* d_in, const int* in_sizes, int n_in,
                              void* d_out, int out_size, void* d_ws, size_t ws_size,
                              hipStream_t stream)
{
    (void)in_sizes; (void)n_in; (void)out_size;
    constexpr int Ns = 8192, Ne = 4096, M = 8192, H = 1024, K3 = 3072, AO = 1024;

    const float* Xss  = (const float*)d_in[0];
    const float* Xes  = (const float*)d_in[1];
    const float* Att  = (const float*)d_in[2];
    const float* Wss  = (const float*)d_in[3];
    const float* bss  = (const float*)d_in[4];
    const float* Wes  = (const float*)d_in[5];
    const float* bes  = (const float*)d_in[6];
    const float* Wlin = (const float*)d_in[7];
    const float* blin = (const float*)d_in[8];
    float* Out = (float*)d_out;

    // ---- workspace layout (static ~216 MB + S chunk) ----
    char* base = (char*)d_ws;
    size_t off = 0;
    auto carve = [&](size_t bytes) {
        char* r = base + off;
        off = (off + bytes + 255) & ~(size_t)255;
        return r;
    };

    f16* Wl16   = (f16*)carve((size_t)AO * K3 * 2);            //  6.3 MB
    f16* Vtes   = (f16*)carve((size_t)H * Ne * 2);             //  8.4 MB
    f16* Vtss   = (f16*)carve((size_t)H * Ns * 2);             // 16.8 MB
    f16* Pes_hi = (f16*)carve((size_t)Ne * H * 2);             //  8.4 MB
    f16* Pes_lo = (f16*)carve((size_t)Ne * H * 2);             //  8.4 MB
    char* PssRg = carve((size_t)2 * Ns * H * 2);               // 33.6 MB (Pss hi/lo -> later Ctxss/Ctxes)
    f16* Pss_hi = (f16*)PssRg;
    f16* Pss_lo = Pss_hi + (size_t)Ns * H;
    char* WtRg  = carve((size_t)M * Ns * 2);                   // 134.2 MB (Wtss -> later Wtes)
    f16* Wtss   = (f16*)WtRg;
    f16* Wtes   = (f16*)WtRg;

    // S chunk takes the remainder
    size_t remain = (ws_size > off) ? ws_size - off : 0;
    int Mc = (int)(remain / ((size_t)Ns * 4));
    Mc = (Mc / 128) * 128;
    if (Mc > M) Mc = M;
    if (Mc < 128) return;  // ws too small: fail loudly
    float* S = (float*)carve((size_t)Mc * Ns * 4);

    // Ctx aliased over Pss region (dead after ss scores complete)
    f16* Ctxss = (f16*)PssRg;
    f16* Ctxes = Ctxss + (size_t)M * H;

    // ---- stage 0: light conversions ----
    conv_f32_f16<<<(AO * K3) / 1024, 256, 0, stream>>>(Wlin, Wl16);
    transpose_f32_to_f16<<<dim3(Ns / 64, H / 64), 256, 0, stream>>>(Xss, Vtss, Ns, H);
    transpose_f32_to_f16<<<dim3(Ne / 64, H / 64), 256, 0, stream>>>(Xes, Vtes, Ne, H);

    // ---- stage 1: projections P = X @ W^T + b (in-kernel split) ----
    gemm_proj<<<dim3(H / 128, Ns / 128), 256, 0, stream>>>(Xss, Wss, bss, H, Pss_hi, Pss_lo);
    gemm_proj<<<dim3(H / 128, Ne / 128), 256, 0, stream>>>(Xes, Wes, bes, H, Pes_hi, Pes_lo);

    // ---- stage 2 (ss): scores -> softmax -> full weight matrix -> ctx ----
    for (int m0 = 0; m0 < M; m0 += Mc) {
        const int mc = (M - m0 < Mc) ? (M - m0) : Mc;
        gemm_score<<<dim3(Ns / 128, mc / 128), 256, 0, stream>>>(
            Att + (size_t)m0 * H, Pss_hi, Pss_lo, Ns, S);
        softmax_row<8><<<mc, 256, 0, stream>>>(S, Wtss + (size_t)m0 * Ns);
    }
    gemm_f16<<<8 * 64, 256, 0, stream>>>(Wtss, Vtss, Ns, H, Ctxss, 8, 64);

    // ---- stage 2 (es): same, reusing Wt region and S ----
    for (int m0 = 0; m0 < M; m0 += Mc) {
        const int mc = (M - m0 < Mc) ? (M - m0) : Mc;
        gemm_score<<<dim3(Ne / 128, mc / 128), 256, 0, stream>>>(
            Att + (size_t)m0 * H, Pes_hi, Pes_lo, Ne, S);
        softmax_row<4><<<mc, 256, 0, stream>>>(S, Wtes + (size_t)m0 * Ne);
    }
    gemm_f16<<<8 * 64, 256, 0, stream>>>(Wtes, Vtes, Ne, H, Ctxes, 8, 64);

    // ---- stage 3: out = tanh([att, ctx_ss, ctx_es] @ Wlin^T + b) ----
    gemm_final<<<8 * 64, 256, 0, stream>>>(
        Att, Ctxss, Ctxes, Wl16, blin, Out);
}